// Round 7
// baseline (428.287 us; speedup 1.0000x reference)
//
#include <hip/hip_runtime.h>

typedef __attribute__((ext_vector_type(8))) short bf16x8;
typedef __attribute__((ext_vector_type(4))) float f32x4;
typedef unsigned short u16;
typedef unsigned int u32;

#define NTOK 144
#define CDIM 192
#define NH 6
#define CH 32
#define C3 576
#define NWIN 64
#define WLON 15
#define SCALE 0.17677669529663687f
#define LOG2E 1.4426950408889634f

// ws layout (bytes)
#define OFF_W1T  0u            // 576*192*2 = 221184
#define OFF_W2T  221184u       // 192*192*2 = 73728
#define OFF_COMB 294912u       // f32 frag layout: 384*81*64*4*4 = 31850496
#define OFF_Q    32145408u     // 960*6*144*32*2 = 53084160
#define OFF_K    85229568u
#define OFF_V    138313728u    // stored transposed: [b][h][ch][144]

__device__ __forceinline__ u16 f2b(float f){
  u32 u = __float_as_uint(f);
  u32 r = u + 0x7FFFu + ((u >> 16) & 1u);   // RNE
  return (u16)(r >> 16);
}
__device__ __forceinline__ u32 pk2(float a, float b){
  return (u32)f2b(a) | ((u32)f2b(b) << 16);
}

// ---------------- prep: transpose weights to bf16 (B-operand wants k-contiguous rows)
extern "C" __global__ __launch_bounds__(256) void prep_weights(
    const float* __restrict__ w1, const float* __restrict__ w2,
    u16* __restrict__ w1t, u16* __restrict__ w2t){
  int idx = blockIdx.x * 256 + threadIdx.x;
  if (idx < CDIM * C3){ int k = idx / C3;  int c = idx - k * C3;  w1t[c * CDIM + k] = f2b(w1[idx]); }
  if (idx < CDIM * CDIM){ int k = idx / CDIM; int c = idx - k * CDIM; w2t[c * CDIM + k] = f2b(w2[idx]); }
}

// ---------------- prep: comb (bias+mask)*LOG2E as f32 in MFMA C-fragment layout.
// attn then uses exp2 directly: exp2((qk*scale + bias + mask)*log2e) with the
// log2e folded into comb and into Q's scale.
extern "C" __global__ __launch_bounds__(192) void prep_comb(
    const float* __restrict__ bt, const float* __restrict__ mask,
    const int* __restrict__ pidx, float* __restrict__ comb){
  int nwh = blockIdx.x;                 // 0..383 = nw*6+h
  int nw = nwh / NH, h = nwh - nw * NH;
  int tl = blockIdx.y * 192 + threadIdx.x;   // 0..5183 = (ti*9+nt)*64+lane
  int ti = tl / 576;
  int rem = tl - ti * 576;
  int nt = rem >> 6, lane = rem & 63;
  int ib = ti * 16 + ((lane >> 4) << 2);
  int j  = nt * 16 + (lane & 15);
  const float* mrow = mask + (size_t)(nw * WLON) * (NTOK * NTOK);
  float4 v;
  float* vp = reinterpret_cast<float*>(&v);
  #pragma unroll
  for (int r = 0; r < 4; ++r){
    int e = (ib + r) * NTOK + j;
    int pi = pidx[e];
    vp[r] = (bt[((size_t)pi * NWIN + nw) * NH + h] + mrow[e]) * LOG2E;
  }
  *reinterpret_cast<float4*>(comb + ((size_t)nwh * 5184 + tl) * 4) = v;
}

// ---------------- K1: qkv = x @ w1 + b1 — A register-resident per wave, B LDS double-buffered.
// Q written pre-scaled by SCALE*LOG2E (softmax exp2 fold).
#define BPAD 200
extern "C" __global__ __launch_bounds__(256, 3) void qkv_gemm(
    const float* __restrict__ x, const u16* __restrict__ w1t, const float* __restrict__ b1,
    u16* __restrict__ qw, u16* __restrict__ kw, u16* __restrict__ vw){
  __shared__ u16 Bl[2][64 * BPAD];   // 2 x 25.6 KB
  const int tid = threadIdx.x;
  const int wid = tid >> 6, lane = tid & 63, l15 = lane & 15, l4 = lane >> 4;
  const size_t row0 = (size_t)blockIdx.x * 128 + wid * 32;
  const f32x4 zz = {0.f, 0.f, 0.f, 0.f};

  bf16x8 af[2][6];
  #pragma unroll
  for (int mf = 0; mf < 2; ++mf){
    const float* src = x + (row0 + mf * 16 + l15) * CDIM + l4 * 8;
    #pragma unroll
    for (int kk = 0; kk < 6; ++kk){
      float4 f0 = *reinterpret_cast<const float4*>(src + kk * 32);
      float4 f1 = *reinterpret_cast<const float4*>(src + kk * 32 + 4);
      union { bf16x8 v; uint4 u; } cv;
      cv.u.x = pk2(f0.x, f0.y); cv.u.y = pk2(f0.z, f0.w);
      cv.u.z = pk2(f1.x, f1.y); cv.u.w = pk2(f1.z, f1.w);
      af[mf][kk] = cv.v;
    }
  }
  int bw_[2], n0_[2];
  #pragma unroll
  for (int mf = 0; mf < 2; ++mf){
    int t0 = (int)row0 + mf * 16 + l4 * 4;
    bw_[mf] = t0 / NTOK; n0_[mf] = t0 - bw_[mf] * NTOK;
  }

  const int sr = tid >> 2, sq = tid & 3;      // staging role: 4 threads/row, 48 u16 each
  {
    const u16* src = w1t + (size_t)sr * CDIM + sq * 48;
    u16* dst = &Bl[0][sr * BPAD + sq * 48];
    #pragma unroll
    for (int i = 0; i < 48; i += 8)
      *reinterpret_cast<uint4*>(dst + i) = *reinterpret_cast<const uint4*>(src + i);
  }

  int cur = 0;
  #pragma unroll 1
  for (int nt = 0; nt < 9; ++nt){
    __syncthreads();
    if (nt < 8){
      const u16* src = w1t + (size_t)((nt + 1) * 64 + sr) * CDIM + sq * 48;
      u16* dst = &Bl[cur ^ 1][sr * BPAD + sq * 48];
      #pragma unroll
      for (int i = 0; i < 48; i += 8)
        *reinterpret_cast<uint4*>(dst + i) = *reinterpret_cast<const uint4*>(src + i);
    }
    f32x4 acc[2][4];
    #pragma unroll
    for (int mf = 0; mf < 2; ++mf)
      #pragma unroll
      for (int nf = 0; nf < 4; ++nf) acc[mf][nf] = zz;
    #pragma unroll
    for (int kk = 0; kk < 6; ++kk){
      bf16x8 bfr[4];
      #pragma unroll
      for (int nf = 0; nf < 4; ++nf)
        bfr[nf] = *reinterpret_cast<const bf16x8*>(&Bl[cur][(nf * 16 + l15) * BPAD + kk * 32 + l4 * 8]);
      #pragma unroll
      for (int mf = 0; mf < 2; ++mf)
        #pragma unroll
        for (int nf = 0; nf < 4; ++nf)
          acc[mf][nf] = __builtin_amdgcn_mfma_f32_16x16x32_bf16(af[mf][kk], bfr[nf], acc[mf][nf], 0, 0, 0);
    }
    int which = nt / 3;
    #pragma unroll
    for (int nf = 0; nf < 4; ++nf){
      int c = nt * 64 + nf * 16 + l15;
      int rem = c - which * CDIM;
      int hh = rem >> 5, chh = rem & 31;
      float bias = b1[c];
      if (which == 2){   // V transposed: one uint2 store per quad
        #pragma unroll
        for (int mf = 0; mf < 2; ++mf){
          uint2 pv;
          pv.x = pk2(acc[mf][nf][0] + bias, acc[mf][nf][1] + bias);
          pv.y = pk2(acc[mf][nf][2] + bias, acc[mf][nf][3] + bias);
          *reinterpret_cast<uint2*>(vw + (((size_t)bw_[mf] * NH + hh) * CH + chh) * NTOK + n0_[mf]) = pv;
        }
      } else {
        u16* base = (which == 0) ? qw : kw;
        float mult = (which == 0) ? (SCALE * LOG2E) : 1.0f;
        #pragma unroll
        for (int mf = 0; mf < 2; ++mf)
          #pragma unroll
          for (int r = 0; r < 4; ++r)
            base[(((size_t)bw_[mf] * NH + hh) * NTOK + n0_[mf] + r) * CH + chh] = f2b((acc[mf][nf][r] + bias) * mult);
      }
    }
    cur ^= 1;
  }
}

// ---------------- K2: attention v4 — 3 windows (same nw group) per block, 1 head.
// cf fragments identical across the 3 windows -> loaded once per mi, reused 3x;
// bb fully unrolled for cross-chain ILP. Even/odd V pairing -> lane owns adjacent
// output cols -> packed u32 stash stores (full 64B lines, no write amplification).
extern "C" __global__ __launch_bounds__(192, 3) void attn_kernel(
    const u16* __restrict__ qw, const u16* __restrict__ kw, const u16* __restrict__ vw,
    const float* __restrict__ comb, float* __restrict__ outbuf){
  __shared__ u16 Pl[3][3][16][40];   // [wave][bb][row][pad40]
  const int tid = threadIdx.x;
  const int bg = blockIdx.x / NH, h = blockIdx.x - bg * NH;
  const int b0 = bg * 3;             // 3 consecutive windows, always within one 15-group
  const int wv = tid >> 6, lane = tid & 63, l15 = lane & 15, l4 = lane >> 4;
  const size_t qkbase0 = ((size_t)b0 * NH + h) * (NTOK * CH);   // +bb*27648
  const size_t vbase0  = ((size_t)b0 * NH + h) * (CH * NTOK);
  const float* cb = comb + ((size_t)((b0 / WLON) * NH + h)) * (5184 * 4);
  u32* stash32 = reinterpret_cast<u32*>(outbuf);
  const f32x4 zz = {0.f, 0.f, 0.f, 0.f};

  #pragma unroll 1
  for (int mi = 0; mi < 3; ++mi){
    const int ti = wv * 3 + mi;
    // comb fragments: shared by all 3 windows of this block
    f32x4 cf[9];
    #pragma unroll
    for (int nt = 0; nt < 9; ++nt)
      cf[nt] = *reinterpret_cast<const f32x4*>(cb + ((size_t)(ti * 9 + nt) * 64 + lane) * 4);

    #pragma unroll
    for (int bb = 0; bb < 3; ++bb){
      const size_t qkbase = qkbase0 + (size_t)bb * (NH * NTOK * CH);
      const size_t vbase  = vbase0  + (size_t)bb * (NH * CH * NTOK);
      bf16x8 aq = *reinterpret_cast<const bf16x8*>(qw + qkbase + (ti * 16 + l15) * CH + l4 * 8);
      f32x4 s[9];
      #pragma unroll
      for (int nt = 0; nt < 9; ++nt){
        bf16x8 bk = *reinterpret_cast<const bf16x8*>(kw + qkbase + (nt * 16 + l15) * CH + l4 * 8);
        s[nt] = __builtin_amdgcn_mfma_f32_16x16x32_bf16(aq, bk, cf[nt], 0, 0, 0);
      }
      // softmax (no max-subtract; scale/log2e pre-folded): p = exp2(s)
      float invs[4];
      #pragma unroll
      for (int r = 0; r < 4; ++r){
        float sum = 0.f;
        #pragma unroll
        for (int nt = 0; nt < 9; ++nt){
          float p = exp2f(s[nt][r]);
          s[nt][r] = p; sum += p;
        }
        #pragma unroll
        for (int off = 8; off; off >>= 1) sum += __shfl_xor(sum, off, 16);
        invs[r] = 1.0f / sum;   // applied at stash
      }
      // PV through per-(wave,bb) P chunk; even/odd V rows -> lane owns cols {2*l15, 2*l15+1}
      u16* Pw = &Pl[wv][bb][0][0];
      f32x4 oe = zz, oo = zz;
      #pragma unroll
      for (int kk = 0; kk < 5; ++kk){
        #pragma unroll
        for (int r = 0; r < 4; ++r){
          Pw[(l4 * 4 + r) * 40 + l15] = f2b(s[2 * kk][r]);
          if (kk < 4) Pw[(l4 * 4 + r) * 40 + 16 + l15] = f2b(s[2 * kk + 1][r]);
        }
        int j0 = kk * 32 + l4 * 8;
        int jc = (j0 < NTOK) ? j0 : 0;          // clamp tail address (stay in-bounds)
        bf16x8 ap = *reinterpret_cast<const bf16x8*>(Pw + l15 * 40 + l4 * 8);
        bf16x8 bve = *reinterpret_cast<const bf16x8*>(vw + vbase + (size_t)(2 * l15) * NTOK + jc);
        bf16x8 bvo = *reinterpret_cast<const bf16x8*>(vw + vbase + (size_t)(2 * l15 + 1) * NTOK + jc);
        if (j0 >= NTOK) ap = bf16x8{0, 0, 0, 0, 0, 0, 0, 0};   // tail K=16: zero P side
        oe = __builtin_amdgcn_mfma_f32_16x16x32_bf16(ap, bve, oe, 0, 0, 0);
        oo = __builtin_amdgcn_mfma_f32_16x16x32_bf16(ap, bvo, oo, 0, 0, 0);
      }
      // packed stash: one u32 (cols 2*l15, 2*l15+1) per row -> full 64B lines
      #pragma unroll
      for (int r = 0; r < 4; ++r){
        size_t t = (size_t)(b0 + bb) * NTOK + ti * 16 + l4 * 4 + r;
        float is = invs[r];
        stash32[t * 192 + 96 + h * 16 + l15] = pk2(oe[r] * is, oo[r] * is);
      }
    }
  }
}

// ---------------- K3: out = attn_out @ w2 + b2 — B register-stationary, one-deep A prefetch.
extern "C" __global__ __launch_bounds__(256, 2) void proj_gemm(
    const u16* __restrict__ w2t, const float* __restrict__ b2, float* __restrict__ outbuf){
  const int tid = threadIdx.x;
  const int wid = tid >> 6, lane = tid & 63, l15 = lane & 15, l4 = lane >> 4;
  const int hb = blockIdx.y;             // col half: cols hb*96 .. +96
  const f32x4 zz = {0.f, 0.f, 0.f, 0.f};

  bf16x8 bfr[6][6];
  #pragma unroll
  for (int nf = 0; nf < 6; ++nf)
    #pragma unroll
    for (int kk = 0; kk < 6; ++kk)
      bfr[nf][kk] = *reinterpret_cast<const bf16x8*>(
          w2t + (size_t)(hb * 96 + nf * 16 + l15) * CDIM + kk * 32 + l4 * 8);

  const u16* stash = reinterpret_cast<const u16*>(outbuf);
  const size_t rbase = (size_t)blockIdx.x * 256 + wid * 64;

#define LOADA(dst, mt) { \
    const u16* src_ = stash + (rbase + (mt) * 16 + l15) * 384 + 192 + l4 * 8; \
    _Pragma("unroll") \
    for (int kk = 0; kk < 6; ++kk) dst[kk] = *reinterpret_cast<const bf16x8*>(src_ + kk * 32); }

#define COMPUTE(a_, mt) { \
    f32x4 acc[6]; \
    _Pragma("unroll") \
    for (int nf = 0; nf < 6; ++nf) acc[nf] = zz; \
    _Pragma("unroll") \
    for (int kk = 0; kk < 6; ++kk) \
      _Pragma("unroll") \
      for (int nf = 0; nf < 6; ++nf) \
        acc[nf] = __builtin_amdgcn_mfma_f32_16x16x32_bf16(a_[kk], bfr[nf][kk], acc[nf], 0, 0, 0); \
    _Pragma("unroll") \
    for (int nf = 0; nf < 6; ++nf){ \
      int c = hb * 96 + nf * 16 + l15; \
      float bias = b2[c]; \
      _Pragma("unroll") \
      for (int r = 0; r < 4; ++r) \
        outbuf[(rbase + (mt) * 16 + l4 * 4 + r) * CDIM + c] = acc[nf][r] + bias; } }

  bf16x8 a0[6], a1[6];
  LOADA(a0, 0)
  LOADA(a1, 1) COMPUTE(a0, 0)
  LOADA(a0, 2) COMPUTE(a1, 1)
  LOADA(a1, 3) COMPUTE(a0, 2)
  COMPUTE(a1, 3)
#undef LOADA
#undef COMPUTE
}

extern "C" void kernel_launch(void* const* d_in, const int* in_sizes, int n_in,
                              void* d_out, int out_size, void* d_ws, size_t ws_size,
                              hipStream_t stream){
  const float* x    = (const float*)d_in[0];
  const float* w1   = (const float*)d_in[1];
  const float* b1   = (const float*)d_in[2];
  const float* w2   = (const float*)d_in[3];
  const float* b2   = (const float*)d_in[4];
  const float* bt   = (const float*)d_in[5];
  const float* mask = (const float*)d_in[6];
  const int*   pidx = (const int*)d_in[7];
  (void)in_sizes; (void)n_in; (void)out_size; (void)ws_size;

  char* ws = (char*)d_ws;
  u16*   w1t  = (u16*)(ws + OFF_W1T);
  u16*   w2t  = (u16*)(ws + OFF_W2T);
  float* comb = (float*)(ws + OFF_COMB);
  u16*   qw   = (u16*)(ws + OFF_Q);
  u16*   kw   = (u16*)(ws + OFF_K);
  u16*   vw   = (u16*)(ws + OFF_V);
  float* out = (float*)d_out;

  prep_weights<<<dim3(432), dim3(256), 0, stream>>>(w1, w2, w1t, w2t);
  prep_comb<<<dim3(384, 27), dim3(192), 0, stream>>>(bt, mask, pidx, comb);
  qkv_gemm<<<dim3(1080), dim3(256), 0, stream>>>(x, w1t, b1, qw, kw, vw);
  attn_kernel<<<dim3(1920), dim3(192), 0, stream>>>(qw, kw, vw, comb, out);
  proj_gemm<<<dim3(540, 2), dim3(256), 0, stream>>>(w2t, b2, out);
}

// Round 9
// 337.043 us; speedup vs baseline: 1.2707x; 1.2707x over previous
//
#include <hip/hip_runtime.h>

typedef __attribute__((ext_vector_type(8))) short bf16x8;
typedef __attribute__((ext_vector_type(4))) float f32x4;
typedef unsigned short u16;
typedef unsigned int u32;

#define NTOK 144
#define CDIM 192
#define NH 6
#define CH 32
#define C3 576
#define NWIN 64
#define WLON 15
#define SCALE 0.17677669529663687f
#define LOG2E 1.4426950408889634f

// ws layout (bytes)
#define OFF_W1T  0u            // 576*192*2 = 221184
#define OFF_W2T  221184u       // 192*192*2 = 73728
#define OFF_COMB 294912u       // f32 frag layout: 384*81*64*4*4 = 31850496
#define OFF_Q    32145408u     // 960*6*144*32*2 = 53084160
#define OFF_K    85229568u
#define OFF_V    138313728u    // stored transposed: [b][h][ch][144]

__device__ __forceinline__ u16 f2b(float f){
  u32 u = __float_as_uint(f);
  u32 r = u + 0x7FFFu + ((u >> 16) & 1u);   // RNE
  return (u16)(r >> 16);
}
__device__ __forceinline__ u32 pk2(float a, float b){
  return (u32)f2b(a) | ((u32)f2b(b) << 16);
}

// ---------------- prep: transpose weights to bf16 (B-operand wants k-contiguous rows)
extern "C" __global__ __launch_bounds__(256) void prep_weights(
    const float* __restrict__ w1, const float* __restrict__ w2,
    u16* __restrict__ w1t, u16* __restrict__ w2t){
  int idx = blockIdx.x * 256 + threadIdx.x;
  if (idx < CDIM * C3){ int k = idx / C3;  int c = idx - k * C3;  w1t[c * CDIM + k] = f2b(w1[idx]); }
  if (idx < CDIM * CDIM){ int k = idx / CDIM; int c = idx - k * CDIM; w2t[c * CDIM + k] = f2b(w2[idx]); }
}

// ---------------- prep: comb (bias+mask)*LOG2E as f32 in MFMA C-fragment layout.
extern "C" __global__ __launch_bounds__(192) void prep_comb(
    const float* __restrict__ bt, const float* __restrict__ mask,
    const int* __restrict__ pidx, float* __restrict__ comb){
  int nwh = blockIdx.x;                 // 0..383 = nw*6+h
  int nw = nwh / NH, h = nwh - nw * NH;
  int tl = blockIdx.y * 192 + threadIdx.x;   // 0..5183 = (ti*9+nt)*64+lane
  int ti = tl / 576;
  int rem = tl - ti * 576;
  int nt = rem >> 6, lane = rem & 63;
  int ib = ti * 16 + ((lane >> 4) << 2);
  int j  = nt * 16 + (lane & 15);
  const float* mrow = mask + (size_t)(nw * WLON) * (NTOK * NTOK);
  float4 v;
  float* vp = reinterpret_cast<float*>(&v);
  #pragma unroll
  for (int r = 0; r < 4; ++r){
    int e = (ib + r) * NTOK + j;
    int pi = pidx[e];
    vp[r] = (bt[((size_t)pi * NWIN + nw) * NH + h] + mrow[e]) * LOG2E;
  }
  *reinterpret_cast<float4*>(comb + ((size_t)nwh * 5184 + tl) * 4) = v;
}

// ---------------- K1: qkv = x @ w1 + b1 — A register-resident per wave, B LDS double-buffered.
// Q written pre-scaled by SCALE*LOG2E (softmax exp2 fold).
#define BPAD 200
extern "C" __global__ __launch_bounds__(256, 3) void qkv_gemm(
    const float* __restrict__ x, const u16* __restrict__ w1t, const float* __restrict__ b1,
    u16* __restrict__ qw, u16* __restrict__ kw, u16* __restrict__ vw){
  __shared__ u16 Bl[2][64 * BPAD];   // 2 x 25.6 KB
  const int tid = threadIdx.x;
  const int wid = tid >> 6, lane = tid & 63, l15 = lane & 15, l4 = lane >> 4;
  const size_t row0 = (size_t)blockIdx.x * 128 + wid * 32;
  const f32x4 zz = {0.f, 0.f, 0.f, 0.f};

  bf16x8 af[2][6];
  #pragma unroll
  for (int mf = 0; mf < 2; ++mf){
    const float* src = x + (row0 + mf * 16 + l15) * CDIM + l4 * 8;
    #pragma unroll
    for (int kk = 0; kk < 6; ++kk){
      float4 f0 = *reinterpret_cast<const float4*>(src + kk * 32);
      float4 f1 = *reinterpret_cast<const float4*>(src + kk * 32 + 4);
      union { bf16x8 v; uint4 u; } cv;
      cv.u.x = pk2(f0.x, f0.y); cv.u.y = pk2(f0.z, f0.w);
      cv.u.z = pk2(f1.x, f1.y); cv.u.w = pk2(f1.z, f1.w);
      af[mf][kk] = cv.v;
    }
  }
  int bw_[2], n0_[2];
  #pragma unroll
  for (int mf = 0; mf < 2; ++mf){
    int t0 = (int)row0 + mf * 16 + l4 * 4;
    bw_[mf] = t0 / NTOK; n0_[mf] = t0 - bw_[mf] * NTOK;
  }

  const int sr = tid >> 2, sq = tid & 3;      // staging role: 4 threads/row, 48 u16 each
  {
    const u16* src = w1t + (size_t)sr * CDIM + sq * 48;
    u16* dst = &Bl[0][sr * BPAD + sq * 48];
    #pragma unroll
    for (int i = 0; i < 48; i += 8)
      *reinterpret_cast<uint4*>(dst + i) = *reinterpret_cast<const uint4*>(src + i);
  }

  int cur = 0;
  #pragma unroll 1
  for (int nt = 0; nt < 9; ++nt){
    __syncthreads();
    if (nt < 8){
      const u16* src = w1t + (size_t)((nt + 1) * 64 + sr) * CDIM + sq * 48;
      u16* dst = &Bl[cur ^ 1][sr * BPAD + sq * 48];
      #pragma unroll
      for (int i = 0; i < 48; i += 8)
        *reinterpret_cast<uint4*>(dst + i) = *reinterpret_cast<const uint4*>(src + i);
    }
    f32x4 acc[2][4];
    #pragma unroll
    for (int mf = 0; mf < 2; ++mf)
      #pragma unroll
      for (int nf = 0; nf < 4; ++nf) acc[mf][nf] = zz;
    #pragma unroll
    for (int kk = 0; kk < 6; ++kk){
      bf16x8 bfr[4];
      #pragma unroll
      for (int nf = 0; nf < 4; ++nf)
        bfr[nf] = *reinterpret_cast<const bf16x8*>(&Bl[cur][(nf * 16 + l15) * BPAD + kk * 32 + l4 * 8]);
      #pragma unroll
      for (int mf = 0; mf < 2; ++mf)
        #pragma unroll
        for (int nf = 0; nf < 4; ++nf)
          acc[mf][nf] = __builtin_amdgcn_mfma_f32_16x16x32_bf16(af[mf][kk], bfr[nf], acc[mf][nf], 0, 0, 0);
    }
    int which = nt / 3;
    #pragma unroll
    for (int nf = 0; nf < 4; ++nf){
      int c = nt * 64 + nf * 16 + l15;
      int rem = c - which * CDIM;
      int hh = rem >> 5, chh = rem & 31;
      float bias = b1[c];
      if (which == 2){   // V transposed: one uint2 store per quad
        #pragma unroll
        for (int mf = 0; mf < 2; ++mf){
          uint2 pv;
          pv.x = pk2(acc[mf][nf][0] + bias, acc[mf][nf][1] + bias);
          pv.y = pk2(acc[mf][nf][2] + bias, acc[mf][nf][3] + bias);
          *reinterpret_cast<uint2*>(vw + (((size_t)bw_[mf] * NH + hh) * CH + chh) * NTOK + n0_[mf]) = pv;
        }
      } else {
        u16* base = (which == 0) ? qw : kw;
        float mult = (which == 0) ? (SCALE * LOG2E) : 1.0f;
        #pragma unroll
        for (int mf = 0; mf < 2; ++mf)
          #pragma unroll
          for (int r = 0; r < 4; ++r)
            base[(((size_t)bw_[mf] * NH + hh) * NTOK + n0_[mf] + r) * CH + chh] = f2b((acc[mf][nf][r] + bias) * mult);
      }
    }
    cur ^= 1;
  }
}

// ---------------- K2: attention v5b — per (window,head) block; K/V^T staged in LDS once.
// Fixes vs v5: V staging uses uint4 (16B) chunks, pad-zero covers cols 144..159 fully,
// VPAD=168 (336B rows, 16B-aligned). XCD-swizzled ids group the 90 blocks sharing a comb
// slice onto one XCD. Even/odd V pairing -> packed u32 stash stores.
#define KPAD 40
#define VPAD 168
extern "C" __global__ __launch_bounds__(192, 4) void attn_kernel(
    const u16* __restrict__ qw, const u16* __restrict__ kw, const u16* __restrict__ vw,
    const float* __restrict__ comb, float* __restrict__ outbuf){
  __shared__ u16 Klds[NTOK * KPAD];     // 11520 B
  __shared__ u16 Vlds[CH * VPAD];       // 10752 B (tok cols 144..159 zeroed)
  __shared__ u16 Pl[3][16][KPAD];       //  3840 B   -> total 26112 B
  const int tid = threadIdx.x;
  // XCD swizzle (bijective on 5760 = 8*720): logical = (bid&7)*720 + bid>>3.
  const int logical = (blockIdx.x & 7) * 720 + (blockIdx.x >> 3);
  const int g = logical / WLON, ww = logical - g * WLON;
  const int nw = g / NH, h = g - nw * NH;
  const int b = nw * WLON + ww;
  const int wv = tid >> 6, lane = tid & 63, l15 = lane & 15, l4 = lane >> 4;
  const size_t qkbase = ((size_t)b * NH + h) * (NTOK * CH);
  const size_t vbase  = ((size_t)b * NH + h) * (CH * NTOK);
  const float* cb = comb + ((size_t)g) * (5184 * 4);
  u32* stash32 = reinterpret_cast<u32*>(outbuf);
  const f32x4 zz = {0.f, 0.f, 0.f, 0.f};

  // ---- stage K [144][KPAD] into LDS: 576 x 16B chunks (4 per row)
  #pragma unroll
  for (int i = 0; i < 3; ++i){
    int c = tid + i * 192;
    int row = c >> 2, q = c & 3;
    *reinterpret_cast<uint4*>(Klds + row * KPAD + q * 8) =
        *reinterpret_cast<const uint4*>(kw + qkbase + row * CH + q * 8);
  }
  // ---- stage V^T [32][VPAD]: 576 x 16B chunks (18 per ch row of 144 u16)
  #pragma unroll
  for (int i = 0; i < 3; ++i){
    int c = tid + i * 192;
    int ch = c / 18, t8 = c - ch * 18;
    *reinterpret_cast<uint4*>(Vlds + ch * VPAD + t8 * 8) =
        *reinterpret_cast<const uint4*>(vw + vbase + ch * NTOK + t8 * 8);
  }
  if (tid < 64){                           // zero V tok-pad cols 144..159 (2 x 16B per row)
    int ch = tid >> 1, q = tid & 1;
    uint4 z; z.x = 0u; z.y = 0u; z.z = 0u; z.w = 0u;
    *reinterpret_cast<uint4*>(Vlds + ch * VPAD + NTOK + q * 8) = z;
  }
  // Q fragments for this wave's 3 tiles: issue before the barrier (overlaps staging)
  bf16x8 aq3[3];
  #pragma unroll
  for (int mi = 0; mi < 3; ++mi)
    aq3[mi] = *reinterpret_cast<const bf16x8*>(qw + qkbase + ((wv * 3 + mi) * 16 + l15) * CH + l4 * 8);
  __syncthreads();

  #pragma unroll 1
  for (int mi = 0; mi < 3; ++mi){
    const int ti = wv * 3 + mi;
    // S = q@k^T + comb (C-init); K frags from LDS
    f32x4 s[9];
    #pragma unroll
    for (int nt = 0; nt < 9; ++nt){
      f32x4 cf = *reinterpret_cast<const f32x4*>(cb + ((size_t)(ti * 9 + nt) * 64 + lane) * 4);
      bf16x8 bk = *reinterpret_cast<const bf16x8*>(Klds + (nt * 16 + l15) * KPAD + l4 * 8);
      s[nt] = __builtin_amdgcn_mfma_f32_16x16x32_bf16(aq3[mi], bk, cf, 0, 0, 0);
    }
    // softmax (no max-subtract; log2e pre-folded): p = exp2(s)
    float invs[4];
    #pragma unroll
    for (int r = 0; r < 4; ++r){
      float sum = 0.f;
      #pragma unroll
      for (int nt = 0; nt < 9; ++nt){
        float p = exp2f(s[nt][r]);
        s[nt][r] = p; sum += p;
      }
      #pragma unroll
      for (int off = 8; off; off >>= 1) sum += __shfl_xor(sum, off, 16);
      invs[r] = 1.0f / sum;   // applied at stash
    }
    // PV through per-wave P chunk; V frags from LDS, even/odd rows -> adjacent out cols
    u16* Pw = &Pl[wv][0][0];
    f32x4 oe = zz, oo = zz;
    #pragma unroll
    for (int kk = 0; kk < 5; ++kk){
      #pragma unroll
      for (int r = 0; r < 4; ++r){
        Pw[(l4 * 4 + r) * KPAD + l15] = f2b(s[2 * kk][r]);
        if (kk < 4) Pw[(l4 * 4 + r) * KPAD + 16 + l15] = f2b(s[2 * kk + 1][r]);
      }
      int j0 = kk * 32 + l4 * 8;
      bf16x8 ap  = *reinterpret_cast<const bf16x8*>(Pw + l15 * KPAD + l4 * 8);
      bf16x8 bve = *reinterpret_cast<const bf16x8*>(Vlds + (2 * l15) * VPAD + j0);
      bf16x8 bvo = *reinterpret_cast<const bf16x8*>(Vlds + (2 * l15 + 1) * VPAD + j0);
      if (j0 >= NTOK) ap = bf16x8{0, 0, 0, 0, 0, 0, 0, 0};   // tail K=16: zero P side
      oe = __builtin_amdgcn_mfma_f32_16x16x32_bf16(ap, bve, oe, 0, 0, 0);
      oo = __builtin_amdgcn_mfma_f32_16x16x32_bf16(ap, bvo, oo, 0, 0, 0);
    }
    // packed stash: one u32 (cols 2*l15, 2*l15+1 of head h) per row -> full 64B lines
    #pragma unroll
    for (int r = 0; r < 4; ++r){
      size_t t = (size_t)b * NTOK + ti * 16 + l4 * 4 + r;
      float is = invs[r];
      stash32[t * 192 + 96 + h * 16 + l15] = pk2(oe[r] * is, oo[r] * is);
    }
  }
}

// ---------------- K3: out = attn_out @ w2 + b2 — B register-stationary, one-deep A prefetch.
extern "C" __global__ __launch_bounds__(256, 2) void proj_gemm(
    const u16* __restrict__ w2t, const float* __restrict__ b2, float* __restrict__ outbuf){
  const int tid = threadIdx.x;
  const int wid = tid >> 6, lane = tid & 63, l15 = lane & 15, l4 = lane >> 4;
  const int hb = blockIdx.y;             // col half: cols hb*96 .. +96
  const f32x4 zz = {0.f, 0.f, 0.f, 0.f};

  bf16x8 bfr[6][6];
  #pragma unroll
  for (int nf = 0; nf < 6; ++nf)
    #pragma unroll
    for (int kk = 0; kk < 6; ++kk)
      bfr[nf][kk] = *reinterpret_cast<const bf16x8*>(
          w2t + (size_t)(hb * 96 + nf * 16 + l15) * CDIM + kk * 32 + l4 * 8);

  const u16* stash = reinterpret_cast<const u16*>(outbuf);
  const size_t rbase = (size_t)blockIdx.x * 256 + wid * 64;

#define LOADA(dst, mt) { \
    const u16* src_ = stash + (rbase + (mt) * 16 + l15) * 384 + 192 + l4 * 8; \
    _Pragma("unroll") \
    for (int kk = 0; kk < 6; ++kk) dst[kk] = *reinterpret_cast<const bf16x8*>(src_ + kk * 32); }

#define COMPUTE(a_, mt) { \
    f32x4 acc[6]; \
    _Pragma("unroll") \
    for (int nf = 0; nf < 6; ++nf) acc[nf] = zz; \
    _Pragma("unroll") \
    for (int kk = 0; kk < 6; ++kk) \
      _Pragma("unroll") \
      for (int nf = 0; nf < 6; ++nf) \
        acc[nf] = __builtin_amdgcn_mfma_f32_16x16x32_bf16(a_[kk], bfr[nf][kk], acc[nf], 0, 0, 0); \
    _Pragma("unroll") \
    for (int nf = 0; nf < 6; ++nf){ \
      int c = hb * 96 + nf * 16 + l15; \
      float bias = b2[c]; \
      _Pragma("unroll") \
      for (int r = 0; r < 4; ++r) \
        outbuf[(rbase + (mt) * 16 + l4 * 4 + r) * CDIM + c] = acc[nf][r] + bias; } }

  bf16x8 a0[6], a1[6];
  LOADA(a0, 0)
  LOADA(a1, 1) COMPUTE(a0, 0)
  LOADA(a0, 2) COMPUTE(a1, 1)
  LOADA(a1, 3) COMPUTE(a0, 2)
  COMPUTE(a1, 3)
#undef LOADA
#undef COMPUTE
}

extern "C" void kernel_launch(void* const* d_in, const int* in_sizes, int n_in,
                              void* d_out, int out_size, void* d_ws, size_t ws_size,
                              hipStream_t stream){
  const float* x    = (const float*)d_in[0];
  const float* w1   = (const float*)d_in[1];
  const float* b1   = (const float*)d_in[2];
  const float* w2   = (const float*)d_in[3];
  const float* b2   = (const float*)d_in[4];
  const float* bt   = (const float*)d_in[5];
  const float* mask = (const float*)d_in[6];
  const int*   pidx = (const int*)d_in[7];
  (void)in_sizes; (void)n_in; (void)out_size; (void)ws_size;

  char* ws = (char*)d_ws;
  u16*   w1t  = (u16*)(ws + OFF_W1T);
  u16*   w2t  = (u16*)(ws + OFF_W2T);
  float* comb = (float*)(ws + OFF_COMB);
  u16*   qw   = (u16*)(ws + OFF_Q);
  u16*   kw   = (u16*)(ws + OFF_K);
  u16*   vw   = (u16*)(ws + OFF_V);
  float* out = (float*)d_out;

  prep_weights<<<dim3(432), dim3(256), 0, stream>>>(w1, w2, w1t, w2t);
  prep_comb<<<dim3(384, 27), dim3(192), 0, stream>>>(bt, mask, pidx, comb);
  qkv_gemm<<<dim3(1080), dim3(256), 0, stream>>>(x, w1t, b1, qw, kw, vw);
  attn_kernel<<<dim3(5760), dim3(192), 0, stream>>>(qw, kw, vw, comb, out);
  proj_gemm<<<dim3(540, 2), dim3(256), 0, stream>>>(w2t, b2, out);
}

// Round 10
// 291.113 us; speedup vs baseline: 1.4712x; 1.1578x over previous
//
#include <hip/hip_runtime.h>

typedef __attribute__((ext_vector_type(8))) short bf16x8;
typedef __attribute__((ext_vector_type(4))) float f32x4;
typedef unsigned short u16;
typedef unsigned int u32;

#define NTOK 144
#define CDIM 192
#define NH 6
#define CH 32
#define C3 576
#define NWIN 64
#define WLON 15
#define SCALE 0.17677669529663687f
#define LOG2E 1.4426950408889634f

// ws layout (bytes)
#define OFF_W1T  0u            // 576*192*2 = 221184
#define OFF_W2T  221184u       // 192*192*2 = 73728
#define OFF_COMB 294912u       // f32 frag layout: 384*81*64*4*4 = 31850496
#define OFF_Q    32145408u     // 960*6*144*32*2 = 53084160
#define OFF_K    85229568u
#define OFF_V    138313728u    // stored transposed: [b][h][ch][144]

__device__ __forceinline__ u16 f2b(float f){
  u32 u = __float_as_uint(f);
  u32 r = u + 0x7FFFu + ((u >> 16) & 1u);   // RNE
  return (u16)(r >> 16);
}
__device__ __forceinline__ u32 pk2(float a, float b){
  return (u32)f2b(a) | ((u32)f2b(b) << 16);
}

// ---------------- prep: transpose weights to bf16 (B-operand wants k-contiguous rows)
extern "C" __global__ __launch_bounds__(256) void prep_weights(
    const float* __restrict__ w1, const float* __restrict__ w2,
    u16* __restrict__ w1t, u16* __restrict__ w2t){
  int idx = blockIdx.x * 256 + threadIdx.x;
  if (idx < CDIM * C3){ int k = idx / C3;  int c = idx - k * C3;  w1t[c * CDIM + k] = f2b(w1[idx]); }
  if (idx < CDIM * CDIM){ int k = idx / CDIM; int c = idx - k * CDIM; w2t[c * CDIM + k] = f2b(w2[idx]); }
}

// ---------------- prep: comb (bias+mask)*LOG2E as f32 in MFMA C-fragment layout.
extern "C" __global__ __launch_bounds__(192) void prep_comb(
    const float* __restrict__ bt, const float* __restrict__ mask,
    const int* __restrict__ pidx, float* __restrict__ comb){
  int nwh = blockIdx.x;                 // 0..383 = nw*6+h
  int nw = nwh / NH, h = nwh - nw * NH;
  int tl = blockIdx.y * 192 + threadIdx.x;   // 0..5183 = (ti*9+nt)*64+lane
  int ti = tl / 576;
  int rem = tl - ti * 576;
  int nt = rem >> 6, lane = rem & 63;
  int ib = ti * 16 + ((lane >> 4) << 2);
  int j  = nt * 16 + (lane & 15);
  const float* mrow = mask + (size_t)(nw * WLON) * (NTOK * NTOK);
  float4 v;
  float* vp = reinterpret_cast<float*>(&v);
  #pragma unroll
  for (int r = 0; r < 4; ++r){
    int e = (ib + r) * NTOK + j;
    int pi = pidx[e];
    vp[r] = (bt[((size_t)pi * NWIN + nw) * NH + h] + mrow[e]) * LOG2E;
  }
  *reinterpret_cast<float4*>(comb + ((size_t)nwh * 5184 + tl) * 4) = v;
}

// ---------------- K1: qkv = x @ w1 + b1 — A register-resident per wave, B LDS double-buffered.
// Q written pre-scaled by SCALE*LOG2E (softmax exp2 fold).
#define BPAD 200
extern "C" __global__ __launch_bounds__(256, 3) void qkv_gemm(
    const float* __restrict__ x, const u16* __restrict__ w1t, const float* __restrict__ b1,
    u16* __restrict__ qw, u16* __restrict__ kw, u16* __restrict__ vw){
  __shared__ u16 Bl[2][64 * BPAD];   // 2 x 25.6 KB
  const int tid = threadIdx.x;
  const int wid = tid >> 6, lane = tid & 63, l15 = lane & 15, l4 = lane >> 4;
  const size_t row0 = (size_t)blockIdx.x * 128 + wid * 32;
  const f32x4 zz = {0.f, 0.f, 0.f, 0.f};

  bf16x8 af[2][6];
  #pragma unroll
  for (int mf = 0; mf < 2; ++mf){
    const float* src = x + (row0 + mf * 16 + l15) * CDIM + l4 * 8;
    #pragma unroll
    for (int kk = 0; kk < 6; ++kk){
      float4 f0 = *reinterpret_cast<const float4*>(src + kk * 32);
      float4 f1 = *reinterpret_cast<const float4*>(src + kk * 32 + 4);
      union { bf16x8 v; uint4 u; } cv;
      cv.u.x = pk2(f0.x, f0.y); cv.u.y = pk2(f0.z, f0.w);
      cv.u.z = pk2(f1.x, f1.y); cv.u.w = pk2(f1.z, f1.w);
      af[mf][kk] = cv.v;
    }
  }
  int bw_[2], n0_[2];
  #pragma unroll
  for (int mf = 0; mf < 2; ++mf){
    int t0 = (int)row0 + mf * 16 + l4 * 4;
    bw_[mf] = t0 / NTOK; n0_[mf] = t0 - bw_[mf] * NTOK;
  }

  const int sr = tid >> 2, sq = tid & 3;      // staging role: 4 threads/row, 48 u16 each
  {
    const u16* src = w1t + (size_t)sr * CDIM + sq * 48;
    u16* dst = &Bl[0][sr * BPAD + sq * 48];
    #pragma unroll
    for (int i = 0; i < 48; i += 8)
      *reinterpret_cast<uint4*>(dst + i) = *reinterpret_cast<const uint4*>(src + i);
  }

  int cur = 0;
  #pragma unroll 1
  for (int nt = 0; nt < 9; ++nt){
    __syncthreads();
    if (nt < 8){
      const u16* src = w1t + (size_t)((nt + 1) * 64 + sr) * CDIM + sq * 48;
      u16* dst = &Bl[cur ^ 1][sr * BPAD + sq * 48];
      #pragma unroll
      for (int i = 0; i < 48; i += 8)
        *reinterpret_cast<uint4*>(dst + i) = *reinterpret_cast<const uint4*>(src + i);
    }
    f32x4 acc[2][4];
    #pragma unroll
    for (int mf = 0; mf < 2; ++mf)
      #pragma unroll
      for (int nf = 0; nf < 4; ++nf) acc[mf][nf] = zz;
    #pragma unroll
    for (int kk = 0; kk < 6; ++kk){
      bf16x8 bfr[4];
      #pragma unroll
      for (int nf = 0; nf < 4; ++nf)
        bfr[nf] = *reinterpret_cast<const bf16x8*>(&Bl[cur][(nf * 16 + l15) * BPAD + kk * 32 + l4 * 8]);
      #pragma unroll
      for (int mf = 0; mf < 2; ++mf)
        #pragma unroll
        for (int nf = 0; nf < 4; ++nf)
          acc[mf][nf] = __builtin_amdgcn_mfma_f32_16x16x32_bf16(af[mf][kk], bfr[nf], acc[mf][nf], 0, 0, 0);
    }
    int which = nt / 3;
    #pragma unroll
    for (int nf = 0; nf < 4; ++nf){
      int c = nt * 64 + nf * 16 + l15;
      int rem = c - which * CDIM;
      int hh = rem >> 5, chh = rem & 31;
      float bias = b1[c];
      if (which == 2){   // V transposed: one uint2 store per quad
        #pragma unroll
        for (int mf = 0; mf < 2; ++mf){
          uint2 pv;
          pv.x = pk2(acc[mf][nf][0] + bias, acc[mf][nf][1] + bias);
          pv.y = pk2(acc[mf][nf][2] + bias, acc[mf][nf][3] + bias);
          *reinterpret_cast<uint2*>(vw + (((size_t)bw_[mf] * NH + hh) * CH + chh) * NTOK + n0_[mf]) = pv;
        }
      } else {
        u16* base = (which == 0) ? qw : kw;
        float mult = (which == 0) ? (SCALE * LOG2E) : 1.0f;
        #pragma unroll
        for (int mf = 0; mf < 2; ++mf)
          #pragma unroll
          for (int r = 0; r < 4; ++r)
            base[(((size_t)bw_[mf] * NH + hh) * NTOK + n0_[mf] + r) * CH + chh] = f2b((acc[mf][nf][r] + bias) * mult);
      }
    }
    cur ^= 1;
  }
}

// ---------------- K2: attention v6 — R6's proven per-wave path, re-shaped launch:
// 512-thread blocks (8 waves), ONE WAVE = ONE (window,head), all 9 m-tiles.
// Tests the 4-workgroups/CU occupancy-cap hypothesis (fatter blocks -> more resident
// waves). K fragments hoisted once per wave (9x reuse). No barriers, no cross-wave LDS.
extern "C" __global__ __launch_bounds__(512, 4) void attn_kernel(
    const u16* __restrict__ qw, const u16* __restrict__ kw, const u16* __restrict__ vw,
    const float* __restrict__ comb, float* __restrict__ outbuf){
  __shared__ u16 Pl[8][16][40];   // per-wave P chunk, pad 40 (10240 B)
  const int tid = threadIdx.x;
  const int wv = tid >> 6, lane = tid & 63, l15 = lane & 15, l4 = lane >> 4;
  const int gw = blockIdx.x * 8 + wv;       // 0..5759 = b*6+h
  const int b = gw / NH, h = gw - b * NH;
  const size_t qkbase = ((size_t)b * NH + h) * (NTOK * CH);
  const size_t vbase  = ((size_t)b * NH + h) * (CH * NTOK);
  const float* cb = comb + ((size_t)((b / WLON) * NH + h)) * (5184 * 4);
  u16* Pw = &Pl[wv][0][0];
  u16* stash = reinterpret_cast<u16*>(outbuf);
  const f32x4 zz = {0.f, 0.f, 0.f, 0.f};

  // K fragments: shared across all 9 m-tiles — load once per wave
  bf16x8 bk[9];
  #pragma unroll
  for (int nt = 0; nt < 9; ++nt)
    bk[nt] = *reinterpret_cast<const bf16x8*>(kw + qkbase + (nt * 16 + l15) * CH + l4 * 8);

  #pragma unroll 1
  for (int ti = 0; ti < 9; ++ti){
    bf16x8 aq = *reinterpret_cast<const bf16x8*>(qw + qkbase + (ti * 16 + l15) * CH + l4 * 8);
    // S = q@k^T + comb (C-init)
    f32x4 s[9];
    #pragma unroll
    for (int nt = 0; nt < 9; ++nt){
      f32x4 cf = *reinterpret_cast<const f32x4*>(cb + ((size_t)(ti * 9 + nt) * 64 + lane) * 4);
      s[nt] = __builtin_amdgcn_mfma_f32_16x16x32_bf16(aq, bk[nt], cf, 0, 0, 0);
    }
    // softmax (no max-subtract; log2e pre-folded): p = exp2(s)
    float invs[4];
    #pragma unroll
    for (int r = 0; r < 4; ++r){
      float sum = 0.f;
      #pragma unroll
      for (int nt = 0; nt < 9; ++nt){
        float p = exp2f(s[nt][r]);
        s[nt][r] = p; sum += p;
      }
      #pragma unroll
      for (int off = 8; off; off >>= 1) sum += __shfl_xor(sum, off, 16);
      invs[r] = 1.0f / sum;   // applied at stash
    }
    // PV through per-wave P chunk; V from global (L1-resident per (b,h))
    f32x4 o0 = zz, o1 = zz;
    #pragma unroll
    for (int kk = 0; kk < 5; ++kk){
      #pragma unroll
      for (int r = 0; r < 4; ++r){
        Pw[(l4 * 4 + r) * 40 + l15] = f2b(s[2 * kk][r]);
        if (kk < 4) Pw[(l4 * 4 + r) * 40 + 16 + l15] = f2b(s[2 * kk + 1][r]);
      }
      int j0 = kk * 32 + l4 * 8;
      int jc = (j0 < NTOK) ? j0 : 0;          // clamp tail address (stay in-bounds)
      bf16x8 ap = *reinterpret_cast<const bf16x8*>(Pw + l15 * 40 + l4 * 8);
      bf16x8 bv0 = *reinterpret_cast<const bf16x8*>(vw + vbase + (size_t)l15 * NTOK + jc);
      bf16x8 bv1 = *reinterpret_cast<const bf16x8*>(vw + vbase + (size_t)(16 + l15) * NTOK + jc);
      if (j0 >= NTOK) ap = bf16x8{0, 0, 0, 0, 0, 0, 0, 0};   // tail K=16: zero P side
      o0 = __builtin_amdgcn_mfma_f32_16x16x32_bf16(ap, bv0, o0, 0, 0, 0);
      o1 = __builtin_amdgcn_mfma_f32_16x16x32_bf16(ap, bv1, o1, 0, 0, 0);
    }
    #pragma unroll
    for (int r = 0; r < 4; ++r){
      size_t t = (size_t)b * NTOK + ti * 16 + l4 * 4 + r;
      float is = invs[r];
      stash[t * 384 + 192 + h * CH + l15]      = f2b(o0[r] * is);
      stash[t * 384 + 192 + h * CH + 16 + l15] = f2b(o1[r] * is);
    }
  }
}

// ---------------- K3: out = attn_out @ w2 + b2 — B register-stationary, one-deep A prefetch.
extern "C" __global__ __launch_bounds__(256, 2) void proj_gemm(
    const u16* __restrict__ w2t, const float* __restrict__ b2, float* __restrict__ outbuf){
  const int tid = threadIdx.x;
  const int wid = tid >> 6, lane = tid & 63, l15 = lane & 15, l4 = lane >> 4;
  const int hb = blockIdx.y;             // col half: cols hb*96 .. +96
  const f32x4 zz = {0.f, 0.f, 0.f, 0.f};

  bf16x8 bfr[6][6];
  #pragma unroll
  for (int nf = 0; nf < 6; ++nf)
    #pragma unroll
    for (int kk = 0; kk < 6; ++kk)
      bfr[nf][kk] = *reinterpret_cast<const bf16x8*>(
          w2t + (size_t)(hb * 96 + nf * 16 + l15) * CDIM + kk * 32 + l4 * 8);

  const u16* stash = reinterpret_cast<const u16*>(outbuf);
  const size_t rbase = (size_t)blockIdx.x * 256 + wid * 64;

#define LOADA(dst, mt) { \
    const u16* src_ = stash + (rbase + (mt) * 16 + l15) * 384 + 192 + l4 * 8; \
    _Pragma("unroll") \
    for (int kk = 0; kk < 6; ++kk) dst[kk] = *reinterpret_cast<const bf16x8*>(src_ + kk * 32); }

#define COMPUTE(a_, mt) { \
    f32x4 acc[6]; \
    _Pragma("unroll") \
    for (int nf = 0; nf < 6; ++nf) acc[nf] = zz; \
    _Pragma("unroll") \
    for (int kk = 0; kk < 6; ++kk) \
      _Pragma("unroll") \
      for (int nf = 0; nf < 6; ++nf) \
        acc[nf] = __builtin_amdgcn_mfma_f32_16x16x32_bf16(a_[kk], bfr[nf][kk], acc[nf], 0, 0, 0); \
    _Pragma("unroll") \
    for (int nf = 0; nf < 6; ++nf){ \
      int c = hb * 96 + nf * 16 + l15; \
      float bias = b2[c]; \
      _Pragma("unroll") \
      for (int r = 0; r < 4; ++r) \
        outbuf[(rbase + (mt) * 16 + l4 * 4 + r) * CDIM + c] = acc[nf][r] + bias; } }

  bf16x8 a0[6], a1[6];
  LOADA(a0, 0)
  LOADA(a1, 1) COMPUTE(a0, 0)
  LOADA(a0, 2) COMPUTE(a1, 1)
  LOADA(a1, 3) COMPUTE(a0, 2)
  COMPUTE(a1, 3)
#undef LOADA
#undef COMPUTE
}

extern "C" void kernel_launch(void* const* d_in, const int* in_sizes, int n_in,
                              void* d_out, int out_size, void* d_ws, size_t ws_size,
                              hipStream_t stream){
  const float* x    = (const float*)d_in[0];
  const float* w1   = (const float*)d_in[1];
  const float* b1   = (const float*)d_in[2];
  const float* w2   = (const float*)d_in[3];
  const float* b2   = (const float*)d_in[4];
  const float* bt   = (const float*)d_in[5];
  const float* mask = (const float*)d_in[6];
  const int*   pidx = (const int*)d_in[7];
  (void)in_sizes; (void)n_in; (void)out_size; (void)ws_size;

  char* ws = (char*)d_ws;
  u16*   w1t  = (u16*)(ws + OFF_W1T);
  u16*   w2t  = (u16*)(ws + OFF_W2T);
  float* comb = (float*)(ws + OFF_COMB);
  u16*   qw   = (u16*)(ws + OFF_Q);
  u16*   kw   = (u16*)(ws + OFF_K);
  u16*   vw   = (u16*)(ws + OFF_V);
  float* out = (float*)d_out;

  prep_weights<<<dim3(432), dim3(256), 0, stream>>>(w1, w2, w1t, w2t);
  prep_comb<<<dim3(384, 27), dim3(192), 0, stream>>>(bt, mask, pidx, comb);
  qkv_gemm<<<dim3(1080), dim3(256), 0, stream>>>(x, w1t, b1, qw, kw, vw);
  attn_kernel<<<dim3(720), dim3(512), 0, stream>>>(qw, kw, vw, comb, out);
  proj_gemm<<<dim3(540, 2), dim3(256), 0, stream>>>(w2t, b2, out);
}

// Round 11
// 247.225 us; speedup vs baseline: 1.7324x; 1.1775x over previous
//
#include <hip/hip_runtime.h>

typedef __attribute__((ext_vector_type(8))) short bf16x8;
typedef __attribute__((ext_vector_type(4))) float f32x4;
typedef unsigned short u16;
typedef unsigned int u32;

#define NTOK 144
#define CDIM 192
#define NH 6
#define CH 32
#define C3 576
#define NWIN 64
#define WLON 15
#define SCALE 0.17677669529663687f
#define LOG2E 1.4426950408889634f

// ws layout (bytes)
#define OFF_W1T  0u            // 576*192*2 = 221184
#define OFF_W2T  221184u       // 192*192*2 = 73728
#define OFF_COMB 294912u       // bf16 frag layout: 384*5184*4*2 = 15925248
#define OFF_Q    16220160u     // 960*6*144*32*2 = 53084160
#define OFF_K    69304320u
#define OFF_V    122388480u    // stored transposed: [b][h][ch][144]

__device__ __forceinline__ u16 f2b(float f){
  u32 u = __float_as_uint(f);
  u32 r = u + 0x7FFFu + ((u >> 16) & 1u);   // RNE
  return (u16)(r >> 16);
}
__device__ __forceinline__ u32 pk2(float a, float b){
  return (u32)f2b(a) | ((u32)f2b(b) << 16);
}

// ---------------- prep: transpose weights to bf16 (B-operand wants k-contiguous rows)
extern "C" __global__ __launch_bounds__(256) void prep_weights(
    const float* __restrict__ w1, const float* __restrict__ w2,
    u16* __restrict__ w1t, u16* __restrict__ w2t){
  int idx = blockIdx.x * 256 + threadIdx.x;
  if (idx < CDIM * C3){ int k = idx / C3;  int c = idx - k * C3;  w1t[c * CDIM + k] = f2b(w1[idx]); }
  if (idx < CDIM * CDIM){ int k = idx / CDIM; int c = idx - k * CDIM; w2t[c * CDIM + k] = f2b(w2[idx]); }
}

// ---------------- prep: comb (bias+mask)*LOG2E as bf16 in MFMA C-fragment layout.
// comb[nwh][ti(9)][nt(9)][lane(64)][r(4)] ; attn unpacks (<<16) to f32 for MFMA C-init.
extern "C" __global__ __launch_bounds__(192) void prep_comb(
    const float* __restrict__ bt, const float* __restrict__ mask,
    const int* __restrict__ pidx, u16* __restrict__ comb){
  int nwh = blockIdx.x;                 // 0..383 = nw*6+h
  int nw = nwh / NH, h = nwh - nw * NH;
  int tl = blockIdx.y * 192 + threadIdx.x;   // 0..5183 = (ti*9+nt)*64+lane
  int ti = tl / 576;
  int rem = tl - ti * 576;
  int nt = rem >> 6, lane = rem & 63;
  int ib = ti * 16 + ((lane >> 4) << 2);
  int j  = nt * 16 + (lane & 15);
  const float* mrow = mask + (size_t)(nw * WLON) * (NTOK * NTOK);
  float v[4];
  #pragma unroll
  for (int r = 0; r < 4; ++r){
    int e = (ib + r) * NTOK + j;
    int pi = pidx[e];
    v[r] = (bt[((size_t)pi * NWIN + nw) * NH + h] + mrow[e]) * LOG2E;
  }
  uint2 out; out.x = pk2(v[0], v[1]); out.y = pk2(v[2], v[3]);
  *reinterpret_cast<uint2*>(comb + ((size_t)nwh * 5184 + tl) * 4) = out;
}

// ---------------- K1: qkv = x @ w1 + b1 — A register-resident per wave, B LDS double-buffered.
// Q written pre-scaled by SCALE*LOG2E (softmax exp2 fold).
#define BPAD 200
extern "C" __global__ __launch_bounds__(256, 3) void qkv_gemm(
    const float* __restrict__ x, const u16* __restrict__ w1t, const float* __restrict__ b1,
    u16* __restrict__ qw, u16* __restrict__ kw, u16* __restrict__ vw){
  __shared__ u16 Bl[2][64 * BPAD];   // 2 x 25.6 KB
  const int tid = threadIdx.x;
  const int wid = tid >> 6, lane = tid & 63, l15 = lane & 15, l4 = lane >> 4;
  const size_t row0 = (size_t)blockIdx.x * 128 + wid * 32;
  const f32x4 zz = {0.f, 0.f, 0.f, 0.f};

  bf16x8 af[2][6];
  #pragma unroll
  for (int mf = 0; mf < 2; ++mf){
    const float* src = x + (row0 + mf * 16 + l15) * CDIM + l4 * 8;
    #pragma unroll
    for (int kk = 0; kk < 6; ++kk){
      float4 f0 = *reinterpret_cast<const float4*>(src + kk * 32);
      float4 f1 = *reinterpret_cast<const float4*>(src + kk * 32 + 4);
      union { bf16x8 v; uint4 u; } cv;
      cv.u.x = pk2(f0.x, f0.y); cv.u.y = pk2(f0.z, f0.w);
      cv.u.z = pk2(f1.x, f1.y); cv.u.w = pk2(f1.z, f1.w);
      af[mf][kk] = cv.v;
    }
  }
  int bw_[2], n0_[2];
  #pragma unroll
  for (int mf = 0; mf < 2; ++mf){
    int t0 = (int)row0 + mf * 16 + l4 * 4;
    bw_[mf] = t0 / NTOK; n0_[mf] = t0 - bw_[mf] * NTOK;
  }

  const int sr = tid >> 2, sq = tid & 3;      // staging role: 4 threads/row, 48 u16 each
  {
    const u16* src = w1t + (size_t)sr * CDIM + sq * 48;
    u16* dst = &Bl[0][sr * BPAD + sq * 48];
    #pragma unroll
    for (int i = 0; i < 48; i += 8)
      *reinterpret_cast<uint4*>(dst + i) = *reinterpret_cast<const uint4*>(src + i);
  }

  int cur = 0;
  #pragma unroll 1
  for (int nt = 0; nt < 9; ++nt){
    __syncthreads();
    if (nt < 8){
      const u16* src = w1t + (size_t)((nt + 1) * 64 + sr) * CDIM + sq * 48;
      u16* dst = &Bl[cur ^ 1][sr * BPAD + sq * 48];
      #pragma unroll
      for (int i = 0; i < 48; i += 8)
        *reinterpret_cast<uint4*>(dst + i) = *reinterpret_cast<const uint4*>(src + i);
    }
    f32x4 acc[2][4];
    #pragma unroll
    for (int mf = 0; mf < 2; ++mf)
      #pragma unroll
      for (int nf = 0; nf < 4; ++nf) acc[mf][nf] = zz;
    #pragma unroll
    for (int kk = 0; kk < 6; ++kk){
      bf16x8 bfr[4];
      #pragma unroll
      for (int nf = 0; nf < 4; ++nf)
        bfr[nf] = *reinterpret_cast<const bf16x8*>(&Bl[cur][(nf * 16 + l15) * BPAD + kk * 32 + l4 * 8]);
      #pragma unroll
      for (int mf = 0; mf < 2; ++mf)
        #pragma unroll
        for (int nf = 0; nf < 4; ++nf)
          acc[mf][nf] = __builtin_amdgcn_mfma_f32_16x16x32_bf16(af[mf][kk], bfr[nf], acc[mf][nf], 0, 0, 0);
    }
    int which = nt / 3;
    #pragma unroll
    for (int nf = 0; nf < 4; ++nf){
      int c = nt * 64 + nf * 16 + l15;
      int rem = c - which * CDIM;
      int hh = rem >> 5, chh = rem & 31;
      float bias = b1[c];
      if (which == 2){   // V transposed: one uint2 store per quad
        #pragma unroll
        for (int mf = 0; mf < 2; ++mf){
          uint2 pv;
          pv.x = pk2(acc[mf][nf][0] + bias, acc[mf][nf][1] + bias);
          pv.y = pk2(acc[mf][nf][2] + bias, acc[mf][nf][3] + bias);
          *reinterpret_cast<uint2*>(vw + (((size_t)bw_[mf] * NH + hh) * CH + chh) * NTOK + n0_[mf]) = pv;
        }
      } else {
        u16* base = (which == 0) ? qw : kw;
        float mult = (which == 0) ? (SCALE * LOG2E) : 1.0f;
        #pragma unroll
        for (int mf = 0; mf < 2; ++mf)
          #pragma unroll
          for (int r = 0; r < 4; ++r)
            base[(((size_t)bw_[mf] * NH + hh) * NTOK + n0_[mf] + r) * CH + chh] = f2b((acc[mf][nf][r] + bias) * mult);
      }
    }
    cur ^= 1;
  }
}

// ---------------- K2: attention v7 — 512-thr blocks, wave = one (b,h) (R10 shape), plus:
// bf16 comb (half traffic, <<16 unpack to C-init), cross-ti comb prefetch (hides the
// load latency that heads the serial chain), even/odd V pairing + packed u32 stash.
extern "C" __global__ __launch_bounds__(512) void attn_kernel(
    const u16* __restrict__ qw, const u16* __restrict__ kw, const u16* __restrict__ vw,
    const u16* __restrict__ comb, float* __restrict__ outbuf){
  __shared__ u16 Pl[8][16][40];   // per-wave P chunk, pad 40 (10240 B)
  const int tid = threadIdx.x;
  const int wv = tid >> 6, lane = tid & 63, l15 = lane & 15, l4 = lane >> 4;
  const int gw = blockIdx.x * 8 + wv;       // 0..5759 = b*6+h
  const int b = gw / NH, h = gw - b * NH;
  const size_t qkbase = ((size_t)b * NH + h) * (NTOK * CH);
  const size_t vbase  = ((size_t)b * NH + h) * (CH * NTOK);
  const u16* cb = comb + ((size_t)((b / WLON) * NH + h)) * (5184 * 4);
  u16* Pw = &Pl[wv][0][0];
  u32* stash32 = reinterpret_cast<u32*>(outbuf);
  const f32x4 zz = {0.f, 0.f, 0.f, 0.f};

  // prologue: comb fragments for ti=0 (bf16, 2 dwords per tile)
  uint2 cc[9];
  #pragma unroll
  for (int nt = 0; nt < 9; ++nt)
    cc[nt] = *reinterpret_cast<const uint2*>(cb + ((size_t)nt * 64 + lane) * 4);

  #pragma unroll 1
  for (int ti = 0; ti < 9; ++ti){
    // prefetch next ti's comb (consumed next iteration -> whole body hides latency)
    const int tin = (ti < 8) ? ti + 1 : ti;
    uint2 ccn[9];
    #pragma unroll
    for (int nt = 0; nt < 9; ++nt)
      ccn[nt] = *reinterpret_cast<const uint2*>(cb + ((size_t)(tin * 9 + nt) * 64 + lane) * 4);

    bf16x8 aq = *reinterpret_cast<const bf16x8*>(qw + qkbase + (ti * 16 + l15) * CH + l4 * 8);
    // S = q@k^T + comb (bf16 comb unpacked <<16 as the C-init)
    f32x4 s[9];
    #pragma unroll
    for (int nt = 0; nt < 9; ++nt){
      f32x4 cf;
      cf[0] = __uint_as_float(cc[nt].x << 16);
      cf[1] = __uint_as_float(cc[nt].x & 0xFFFF0000u);
      cf[2] = __uint_as_float(cc[nt].y << 16);
      cf[3] = __uint_as_float(cc[nt].y & 0xFFFF0000u);
      bf16x8 bk = *reinterpret_cast<const bf16x8*>(kw + qkbase + (nt * 16 + l15) * CH + l4 * 8);
      s[nt] = __builtin_amdgcn_mfma_f32_16x16x32_bf16(aq, bk, cf, 0, 0, 0);
    }
    // softmax (no max-subtract; log2e pre-folded): p = exp2(s)
    float invs[4];
    #pragma unroll
    for (int r = 0; r < 4; ++r){
      float sum = 0.f;
      #pragma unroll
      for (int nt = 0; nt < 9; ++nt){
        float p = exp2f(s[nt][r]);
        s[nt][r] = p; sum += p;
      }
      #pragma unroll
      for (int off = 8; off; off >>= 1) sum += __shfl_xor(sum, off, 16);
      invs[r] = 1.0f / sum;   // applied at stash
    }
    // PV through per-wave P chunk; even/odd V rows -> lane owns adjacent output cols
    f32x4 oe = zz, oo = zz;
    #pragma unroll
    for (int kk = 0; kk < 5; ++kk){
      #pragma unroll
      for (int r = 0; r < 4; ++r){
        Pw[(l4 * 4 + r) * 40 + l15] = f2b(s[2 * kk][r]);
        if (kk < 4) Pw[(l4 * 4 + r) * 40 + 16 + l15] = f2b(s[2 * kk + 1][r]);
      }
      int j0 = kk * 32 + l4 * 8;
      int jc = (j0 < NTOK) ? j0 : 0;          // clamp tail address (stay in-bounds)
      bf16x8 ap = *reinterpret_cast<const bf16x8*>(Pw + l15 * 40 + l4 * 8);
      bf16x8 bve = *reinterpret_cast<const bf16x8*>(vw + vbase + (size_t)(2 * l15) * NTOK + jc);
      bf16x8 bvo = *reinterpret_cast<const bf16x8*>(vw + vbase + (size_t)(2 * l15 + 1) * NTOK + jc);
      if (j0 >= NTOK) ap = bf16x8{0, 0, 0, 0, 0, 0, 0, 0};   // tail K=16: zero P side
      oe = __builtin_amdgcn_mfma_f32_16x16x32_bf16(ap, bve, oe, 0, 0, 0);
      oo = __builtin_amdgcn_mfma_f32_16x16x32_bf16(ap, bvo, oo, 0, 0, 0);
    }
    // packed stash: one u32 (cols 2*l15, 2*l15+1 of head h) per row -> full 64B lines
    #pragma unroll
    for (int r = 0; r < 4; ++r){
      size_t t = (size_t)b * NTOK + ti * 16 + l4 * 4 + r;
      float is = invs[r];
      stash32[t * 192 + 96 + h * 16 + l15] = pk2(oe[r] * is, oo[r] * is);
    }
    // rotate prefetch
    #pragma unroll
    for (int nt = 0; nt < 9; ++nt) cc[nt] = ccn[nt];
  }
}

// ---------------- K3: out = attn_out @ w2 + b2 — B register-stationary, one-deep A prefetch.
extern "C" __global__ __launch_bounds__(256, 2) void proj_gemm(
    const u16* __restrict__ w2t, const float* __restrict__ b2, float* __restrict__ outbuf){
  const int tid = threadIdx.x;
  const int wid = tid >> 6, lane = tid & 63, l15 = lane & 15, l4 = lane >> 4;
  const int hb = blockIdx.y;             // col half: cols hb*96 .. +96
  const f32x4 zz = {0.f, 0.f, 0.f, 0.f};

  bf16x8 bfr[6][6];
  #pragma unroll
  for (int nf = 0; nf < 6; ++nf)
    #pragma unroll
    for (int kk = 0; kk < 6; ++kk)
      bfr[nf][kk] = *reinterpret_cast<const bf16x8*>(
          w2t + (size_t)(hb * 96 + nf * 16 + l15) * CDIM + kk * 32 + l4 * 8);

  const u16* stash = reinterpret_cast<const u16*>(outbuf);
  const size_t rbase = (size_t)blockIdx.x * 256 + wid * 64;

#define LOADA(dst, mt) { \
    const u16* src_ = stash + (rbase + (mt) * 16 + l15) * 384 + 192 + l4 * 8; \
    _Pragma("unroll") \
    for (int kk = 0; kk < 6; ++kk) dst[kk] = *reinterpret_cast<const bf16x8*>(src_ + kk * 32); }

#define COMPUTE(a_, mt) { \
    f32x4 acc[6]; \
    _Pragma("unroll") \
    for (int nf = 0; nf < 6; ++nf) acc[nf] = zz; \
    _Pragma("unroll") \
    for (int kk = 0; kk < 6; ++kk) \
      _Pragma("unroll") \
      for (int nf = 0; nf < 6; ++nf) \
        acc[nf] = __builtin_amdgcn_mfma_f32_16x16x32_bf16(a_[kk], bfr[nf][kk], acc[nf], 0, 0, 0); \
    _Pragma("unroll") \
    for (int nf = 0; nf < 6; ++nf){ \
      int c = hb * 96 + nf * 16 + l15; \
      float bias = b2[c]; \
      _Pragma("unroll") \
      for (int r = 0; r < 4; ++r) \
        outbuf[(rbase + (mt) * 16 + l4 * 4 + r) * CDIM + c] = acc[nf][r] + bias; } }

  bf16x8 a0[6], a1[6];
  LOADA(a0, 0)
  LOADA(a1, 1) COMPUTE(a0, 0)
  LOADA(a0, 2) COMPUTE(a1, 1)
  LOADA(a1, 3) COMPUTE(a0, 2)
  COMPUTE(a1, 3)
#undef LOADA
#undef COMPUTE
}

extern "C" void kernel_launch(void* const* d_in, const int* in_sizes, int n_in,
                              void* d_out, int out_size, void* d_ws, size_t ws_size,
                              hipStream_t stream){
  const float* x    = (const float*)d_in[0];
  const float* w1   = (const float*)d_in[1];
  const float* b1   = (const float*)d_in[2];
  const float* w2   = (const float*)d_in[3];
  const float* b2   = (const float*)d_in[4];
  const float* bt   = (const float*)d_in[5];
  const float* mask = (const float*)d_in[6];
  const int*   pidx = (const int*)d_in[7];
  (void)in_sizes; (void)n_in; (void)out_size; (void)ws_size;

  char* ws = (char*)d_ws;
  u16*   w1t  = (u16*)(ws + OFF_W1T);
  u16*   w2t  = (u16*)(ws + OFF_W2T);
  u16*   comb = (u16*)(ws + OFF_COMB);
  u16*   qw   = (u16*)(ws + OFF_Q);
  u16*   kw   = (u16*)(ws + OFF_K);
  u16*   vw   = (u16*)(ws + OFF_V);
  float* out = (float*)d_out;

  prep_weights<<<dim3(432), dim3(256), 0, stream>>>(w1, w2, w1t, w2t);
  prep_comb<<<dim3(384, 27), dim3(192), 0, stream>>>(bt, mask, pidx, comb);
  qkv_gemm<<<dim3(1080), dim3(256), 0, stream>>>(x, w1t, b1, qw, kw, vw);
  attn_kernel<<<dim3(720), dim3(512), 0, stream>>>(qw, kw, vw, comb, out);
  proj_gemm<<<dim3(540, 2), dim3(256), 0, stream>>>(w2t, b2, out);
}